// Round 2
// baseline (90.352 us; speedup 1.0000x reference)
//
#include <hip/hip_runtime.h>

// SSF_Extractor: out = x * resize_bilinear_ac(local_unbiased_var_5x5(x), H, W)
// x: (8, 64, 256, 256) fp32.
//
// Row-streaming design: one block = one 32-row full-width strip of one image.
// Thread t owns column t. Vertical 5-row sums maintained as sliding
// (add-new / subtract-old) register sums with a statically-unrolled 4-deep
// ring; horizontal 5-tap + variance through a 2-row double-buffered LDS
// strip (one barrier per var row); bilinear upsample + x-multiply from LDS.

namespace {

constexpr int H = 256, W = 256;
constexpr int STRIP = 32;           // output rows per block
constexpr int NSTRIP = H / STRIP;   // 8
constexpr int VRMAX = 33;           // max var rows per strip

#define SCALE_F (251.0f / 255.0f)   // align_corners scale (h-1)/(H-1)

__global__ __launch_bounds__(256, 4) void ssf_stream(const float* __restrict__ x,
                                                     float* __restrict__ out) {
  __shared__ float svar[VRMAX][W];  // variance rows for this strip
  __shared__ float scs[2][W];       // column 5-sums, double-buffered
  __shared__ float scss[2][W];      // column 5-sums of squares

  const int t = threadIdx.x;
  const int img = blockIdx.x >> 3;          // 512 images
  const int y0 = (blockIdx.x & 7) * STRIP;  // strip base row

  const float* xi = x + (size_t)img * (H * W);
  float* oi = out + (size_t)img * (H * W);

  const int vymin = (int)floorf((float)y0 * SCALE_F);
  int vymax = (int)floorf((float)(y0 + STRIP - 1) * SCALE_F) + 1;
  if (vymax > 251) vymax = 251;
  const int VR = vymax - vymin + 1;  // <= 33 (uniform across block)

  // Clamped horizontal base: thread t computes var col t (t<252 valid);
  // t>=252 computes harmless garbage into unread LDS cols.
  const int cb = (t < 251) ? t : 251;

  // ---- Phase 1: stream x rows, sliding vertical sums, horizontal var ----
  const float* colp = xi + (size_t)vymin * W + t;
  float r0 = colp[0 * W], r1 = colp[1 * W], r2 = colp[2 * W], r3 = colp[3 * W];
  colp += 4 * W;
  float s = r0 + r1 + r2 + r3;                       // 4-row partial sum
  float s2 = r0 * r0 + r1 * r1 + r2 * r2 + r3 * r3;  // 4-row partial sumsq

  int v = 0;  // uniform across block; guards are block-uniform -> barrier safe
#define VSTEP(OLD, B)                                                       \
  if (v < VR) {                                                             \
    float xn = *colp;                                                       \
    colp += W;                                                              \
    float s5 = s + xn;                                                      \
    float q5 = fmaf(xn, xn, s2);                                            \
    scs[B][t] = s5;                                                         \
    scss[B][t] = q5;                                                        \
    s = s5 - OLD;                                                           \
    s2 = q5 - OLD * OLD;                                                    \
    OLD = xn;                                                               \
    __syncthreads();                                                        \
    float ss = scs[B][cb] + scs[B][cb + 1] + scs[B][cb + 2] +               \
               scs[B][cb + 3] + scs[B][cb + 4];                             \
    float qq = scss[B][cb] + scss[B][cb + 1] + scss[B][cb + 2] +            \
               scss[B][cb + 3] + scss[B][cb + 4];                           \
    svar[v][t] = (qq - ss * ss * (1.0f / 25.0f)) * (1.0f / 24.0f);          \
    ++v;                                                                    \
  }

  // v at loop top is always a multiple of 4 (guards fail monotonically),
  // so buffer parity per position is the literal 0,1,0,1.
  while (v < VR) {
    VSTEP(r0, 0)
    VSTEP(r1, 1)
    VSTEP(r2, 0)
    VSTEP(r3, 1)
  }
#undef VSTEP

  __syncthreads();

  // ---- Phase 2: bilinear upsample + multiply by x ----
  float xs = (float)t * SCALE_F;
  int x0i = (int)floorf(xs);
  float wx = xs - (float)x0i;
  int x1i = x0i + 1;
  if (x1i > 251) x1i = 251;
  float omwx = 1.0f - wx;

  const float* xr = xi + (size_t)y0 * W + t;
  float* orow = oi + (size_t)y0 * W + t;

#pragma unroll 4
  for (int j = 0; j < STRIP; ++j) {
    float ys = (float)(y0 + j) * SCALE_F;
    int vy = (int)floorf(ys);
    float wy = ys - (float)vy;
    int yl0 = vy - vymin;
    int vy1 = vy + 1;
    if (vy1 > 251) vy1 = 251;
    int yl1 = vy1 - vymin;
    float v00 = svar[yl0][x0i], v01 = svar[yl0][x1i];
    float v10 = svar[yl1][x0i], v11 = svar[yl1][x1i];
    float omwy = 1.0f - wy;
    // Match reference order: rows (wy) first, then cols (wx).
    float left = v00 * omwy + v10 * wy;
    float right = v01 * omwy + v11 * wy;
    float val = left * omwx + right * wx;
    orow[j * W] = xr[j * W] * val;
  }
}

}  // namespace

extern "C" void kernel_launch(void* const* d_in, const int* in_sizes, int n_in,
                              void* d_out, int out_size, void* d_ws, size_t ws_size,
                              hipStream_t stream) {
  const float* x = (const float*)d_in[0];
  float* out = (float*)d_out;
  ssf_stream<<<dim3(512 * NSTRIP), dim3(256), 0, stream>>>(x, out);
}

// Round 3
// 74.153 us; speedup vs baseline: 1.2185x; 1.2185x over previous
//
#include <hip/hip_runtime.h>

// SSF_Extractor: out = x * resize_bilinear_ac(local_unbiased_var_5x5(x), H, W)
// x: (8, 64, 256, 256) fp32.
//
// Row-streaming with full register preload: one block = one 32-row full-width
// strip. Thread t owns column t. The 37 x-rows of the column are preloaded
// into registers (37 independent loads in flight -> latency hidden), then the
// 33 var rows are produced by a fully-unrolled register/LDS loop (one barrier
// per row, double-buffered column-sum strips). Phase 2 bilinear-upsamples from
// LDS and multiplies by x (reload hits L2/L3).

namespace {

constexpr int H = 256, W = 256;
constexpr int STRIP = 32;           // output rows per block
constexpr int VRMAX = 33;           // max var rows per strip
constexpr int XR = 37;              // max x rows per strip

#define SCALE_F (251.0f / 255.0f)   // align_corners scale (h-1)/(H-1)

__global__ __launch_bounds__(256, 4) void ssf_stream(const float* __restrict__ x,
                                                     float* __restrict__ out) {
  __shared__ float svar[VRMAX][W];  // variance rows for this strip
  __shared__ float scs[2][W];       // column 5-sums, double-buffered
  __shared__ float scss[2][W];      // column 5-sums of squares

  const int t = threadIdx.x;
  const int img = blockIdx.x >> 3;          // 512 images
  const int y0 = (blockIdx.x & 7) * STRIP;  // strip base row

  const float* xi = x + (size_t)img * (H * W);
  float* oi = out + (size_t)img * (H * W);

  const int vymin = (int)floorf((float)y0 * SCALE_F);
  int vymax = (int)floorf((float)(y0 + STRIP - 1) * SCALE_F) + 1;
  if (vymax > 251) vymax = 251;
  const int VR = vymax - vymin + 1;  // 32 or 33, block-uniform
  const int rmax = VR + 3;           // last needed x-row offset (<= 36)

  // Clamped horizontal base: thread t computes var col t (t<252 valid);
  // t>=252 writes harmless values into unread LDS cols.
  const int cb = (t < 251) ? t : 251;

  // ---- Preload the whole column strip into registers (independent loads) ---
  const float* colp = xi + (size_t)vymin * W + t;
  float R[XR];
#pragma unroll
  for (int i = 0; i < XR; ++i) {
    int rr = i <= rmax ? i : rmax;   // duplicate last row if VR==32
    R[i] = colp[(size_t)rr * W];
  }

  // ---- Phase 1: 33 var rows, pure register/LDS (fully unrolled) ----
#pragma unroll
  for (int v = 0; v < VRMAX; ++v) {
    if (v < VR) {  // block-uniform guard -> barrier-safe
      const int B = v & 1;
      float a0 = R[v], a1 = R[v + 1], a2 = R[v + 2], a3 = R[v + 3], a4 = R[v + 4];
      float s5 = ((a0 + a1) + (a2 + a3)) + a4;
      float q5 = fmaf(a0, a0, fmaf(a1, a1, fmaf(a2, a2, fmaf(a3, a3, a4 * a4))));
      scs[B][t] = s5;
      scss[B][t] = q5;
      __syncthreads();
      float ss = ((scs[B][cb] + scs[B][cb + 1]) + (scs[B][cb + 2] + scs[B][cb + 3])) +
                 scs[B][cb + 4];
      float qq = ((scss[B][cb] + scss[B][cb + 1]) + (scss[B][cb + 2] + scss[B][cb + 3])) +
                 scss[B][cb + 4];
      svar[v][t] = (qq - ss * ss * (1.0f / 25.0f)) * (1.0f / 24.0f);
      // Double buffer + the barrier above make write(B^1) at row v+1 safe
      // against stragglers still reading B^1 from row v-1.
    }
  }
  __syncthreads();

  // ---- Phase 2: bilinear upsample + multiply by x ----
  float xs = (float)t * SCALE_F;
  int x0i = (int)floorf(xs);
  float wx = xs - (float)x0i;
  int x1i = x0i + 1;
  if (x1i > 251) x1i = 251;
  float omwx = 1.0f - wx;

  const float* xr = xi + (size_t)y0 * W + t;
  float* orow = oi + (size_t)y0 * W + t;

#pragma unroll 8
  for (int j = 0; j < STRIP; ++j) {
    float ys = (float)(y0 + j) * SCALE_F;
    int vy = (int)floorf(ys);
    float wy = ys - (float)vy;
    int yl0 = vy - vymin;
    int vy1 = vy + 1;
    if (vy1 > 251) vy1 = 251;
    int yl1 = vy1 - vymin;
    float v00 = svar[yl0][x0i], v01 = svar[yl0][x1i];
    float v10 = svar[yl1][x0i], v11 = svar[yl1][x1i];
    float omwy = 1.0f - wy;
    // Match reference order: rows (wy) first, then cols (wx).
    float left = v00 * omwy + v10 * wy;
    float right = v01 * omwy + v11 * wy;
    float val = left * omwx + right * wx;
    orow[j * W] = xr[j * W] * val;
  }
}

}  // namespace

extern "C" void kernel_launch(void* const* d_in, const int* in_sizes, int n_in,
                              void* d_out, int out_size, void* d_ws, size_t ws_size,
                              hipStream_t stream) {
  const float* x = (const float*)d_in[0];
  float* out = (float*)d_out;
  ssf_stream<<<dim3(512 * (H / STRIP)), dim3(256), 0, stream>>>(x, out);
}

// Round 4
// 63.551 us; speedup vs baseline: 1.4217x; 1.1668x over previous
//
#include <hip/hip_runtime.h>

// SSF_Extractor: out = x * resize_bilinear_ac(local_unbiased_var_5x5(x), 256, 256)
// x: (8, 64, 256, 256) fp32.
//
// Wave-synchronous design: one 64-lane wave owns one 32-output-row full-width
// strip; lane l owns columns 4l..4l+3. Vertical 5-row sliding sums live in
// registers; the horizontal 5-tap uses a right-neighbor exchange through LDS
// (b128, conflict-free, in-order within the wave -> NO barriers anywhere);
// variance rows go to a 2-row LDS ring; output rows are emitted eagerly as
// their two var rows become available, with row-carry reuse of the 5 gathered
// var values per lane.

namespace {

constexpr int W = 256;
#define SC (251.0f / 255.0f)  // align_corners scale (h-1)/(H-1)

__global__ __launch_bounds__(256, 4) void ssf_wave(const float* __restrict__ x,
                                                   float* __restrict__ out) {
  __shared__ float lds[4][1024];  // per wave: sbuf[256] | qbuf[256] | ring[2][256]

  const int tid = threadIdx.x;
  const int lane = tid & 63;
  const int wv = tid >> 6;

  float* const sbuf = &lds[wv][0];
  float* const qbuf = &lds[wv][256];
  float* const ring = &lds[wv][512];

  // XCD-chunked block swizzle (1024 blocks, 8 XCDs, 1024%8==0 -> bijective).
  const int b = blockIdx.x;
  const int bs = (b & 7) * 128 + (b >> 3);
  const int sid = __builtin_amdgcn_readfirstlane(bs * 4 + wv);
  const int img = sid >> 3;                // 0..511
  const int y0 = (sid & 7) * 32;           // strip base output row

  const float* const xi = x + (size_t)img * (W * W);
  float* const oi = out + (size_t)img * (W * W);

  const int vymin = (y0 * 251) / 255;
  int vymax = ((y0 + 31) * 251) / 255 + 1;
  if (vymax > 251) vymax = 251;
  const int VR = vymax - vymin + 1;  // 32 or 33, wave-uniform
  // x rows needed: vymin .. vymax+4 (<= 255 always; no clamping needed).

  const int c0 = lane * 4;

  // ---- Per-lane horizontal bilinear constants ----
  // q0 = x0i(c0); for col c0+i: x0i - q0 in {i-1, i} (i=0 -> 0), x1i - q0 in {i, i+1}.
  const int q0 = (int)floorf((float)c0 * SC);
  float wxv[4];
  bool selA[4], selB[4];
#pragma unroll
  for (int i = 0; i < 4; ++i) {
    float xs = (float)(c0 + i) * SC;
    float x0f = floorf(xs);
    int x0 = (int)x0f;
    wxv[i] = xs - x0f;
    selA[i] = (x0 - q0) == i;
    int x1 = x0 + 1;
    if (x1 > 251) x1 = 251;
    selB[i] = (x1 - q0) == (i + 1);
  }

  // ---- Init vertical partial sums over x rows vymin..vymin+3 ----
  const float* const xrow = xi + (size_t)vymin * W + c0;
  float sacc[4] = {0.f, 0.f, 0.f, 0.f};
  float qacc[4] = {0.f, 0.f, 0.f, 0.f};
  float4 xo = {0.f, 0.f, 0.f, 0.f}, xn;
#pragma unroll
  for (int r = 0; r < 4; ++r) {
    float4 xv = *(const float4*)(xrow + r * W);
    float xa[4] = {xv.x, xv.y, xv.z, xv.w};
#pragma unroll
    for (int i = 0; i < 4; ++i) {
      sacc[i] += xa[i];
      qacc[i] = fmaf(xa[i], xa[i], qacc[i]);
    }
    if (r == 0) xo = xv;
  }
  xn = *(const float4*)(xrow + 4 * W);

  int jn = 0, cur = -1000;
  float vl[5], vh[5];
#pragma unroll
  for (int i = 0; i < 5; ++i) { vl[i] = 0.f; vh[i] = 0.f; }

  for (int v = 0; v < VR; ++v) {
    // Prefetch next iteration's two x rows (hides L1/L2 latency).
    float4 xn2, xo2;
    if (v + 1 < VR) {
      xn2 = *(const float4*)(xrow + (size_t)(v + 5) * W);
      xo2 = *(const float4*)(xrow + (size_t)(v + 1) * W);
    }
    float xna[4] = {xn.x, xn.y, xn.z, xn.w};
    float xoa[4] = {xo.x, xo.y, xo.z, xo.w};
    float s5[4], q5[4];
#pragma unroll
    for (int i = 0; i < 4; ++i) {
      s5[i] = sacc[i] + xna[i];
      q5[i] = fmaf(xna[i], xna[i], qacc[i]);
    }
    // Export own 4 column-sums; import right neighbor's (in-order DS, no barrier).
    *(float4*)(sbuf + c0) = make_float4(s5[0], s5[1], s5[2], s5[3]);
    *(float4*)(qbuf + c0) = make_float4(q5[0], q5[1], q5[2], q5[3]);
    const int nb = (lane < 63) ? (c0 + 4) : c0;  // lane 63 computes unused junk
    float4 ns = *(const float4*)(sbuf + nb);
    float4 nq = *(const float4*)(qbuf + nb);
    // Horizontal 5-tap (sliding) + unbiased variance for var cols c0..c0+3.
    float hs0 = ((s5[0] + s5[1]) + (s5[2] + s5[3])) + ns.x;
    float hq0 = ((q5[0] + q5[1]) + (q5[2] + q5[3])) + nq.x;
    float hs1 = hs0 - s5[0] + ns.y;
    float hq1 = hq0 - q5[0] + nq.y;
    float hs2 = hs1 - s5[1] + ns.z;
    float hq2 = hq1 - q5[1] + nq.z;
    float hs3 = hs2 - s5[2] + ns.w;
    float hq3 = hq2 - q5[2] + nq.w;
    float4 vr4;
    vr4.x = (hq0 - hs0 * hs0 * (1.0f / 25.0f)) * (1.0f / 24.0f);
    vr4.y = (hq1 - hs1 * hs1 * (1.0f / 25.0f)) * (1.0f / 24.0f);
    vr4.z = (hq2 - hs2 * hs2 * (1.0f / 25.0f)) * (1.0f / 24.0f);
    vr4.w = (hq3 - hs3 * hs3 * (1.0f / 25.0f)) * (1.0f / 24.0f);
    *(float4*)(ring + (v & 1) * 256 + c0) = vr4;
    // Slide the vertical window down one row.
#pragma unroll
    for (int i = 0; i < 4; ++i) {
      sacc[i] = s5[i] - xoa[i];
      qacc[i] = fmaf(-xoa[i], xoa[i], q5[i]);
    }
    xn = xn2;
    xo = xo2;

    // ---- Emit output rows whose two var rows are now in the ring ----
    while (jn < 32) {
      int gy = y0 + jn;
      int vy = (gy * 251) / 255;  // exact integer floor
      int vy1 = vy + 1;
      if (vy1 > 251) vy1 = 251;
      if (vy1 - vymin > v) break;  // not ready yet (wave-uniform)
      float ys = (float)gy * SC;
      float wy = ys - (float)vy;   // may be ~-1e-5 at gy=255; harmless
      int vrr = vy - vymin;
      if (vrr != cur) {
        if (vrr == cur + 1) {
#pragma unroll
          for (int i = 0; i < 5; ++i) vl[i] = vh[i];  // row-carry reuse
        } else {
          const float* rl = ring + (vrr & 1) * 256 + q0;
#pragma unroll
          for (int i = 0; i < 5; ++i) vl[i] = rl[i];
        }
        if (vy >= 251) {
#pragma unroll
          for (int i = 0; i < 5; ++i) vh[i] = vl[i];  // bottom clamp
        } else {
          const float* rh = ring + ((vrr + 1) & 1) * 256 + q0;
#pragma unroll
          for (int i = 0; i < 5; ++i) vh[i] = rh[i];
        }
        cur = vrr;
      }
      float4 xv = *(const float4*)(xi + (size_t)gy * W + c0);
      float xa2[4] = {xv.x, xv.y, xv.z, xv.w};
      float omwy = 1.0f - wy;
      float res[4];
#pragma unroll
      for (int i = 0; i < 4; ++i) {
        float a00 = (i == 0) ? vl[0] : (selA[i] ? vl[i] : vl[i - 1]);
        float a10 = (i == 0) ? vh[0] : (selA[i] ? vh[i] : vh[i - 1]);
        float a01 = selB[i] ? vl[i + 1] : vl[i];
        float a11 = selB[i] ? vh[i + 1] : vh[i];
        // Reference order: rows (wy) first, then cols (wx).
        float left = a00 * omwy + a10 * wy;
        float right = a01 * omwy + a11 * wy;
        res[i] = (left * (1.0f - wxv[i]) + right * wxv[i]) * xa2[i];
      }
      *(float4*)(oi + (size_t)gy * W + c0) =
          make_float4(res[0], res[1], res[2], res[3]);
      ++jn;
    }
  }
}

}  // namespace

extern "C" void kernel_launch(void* const* d_in, const int* in_sizes, int n_in,
                              void* d_out, int out_size, void* d_ws, size_t ws_size,
                              hipStream_t stream) {
  const float* x = (const float*)d_in[0];
  float* out = (float*)d_out;
  // 4096 strips (512 images x 8 strips), 4 waves (strips) per 256-thread block.
  ssf_wave<<<dim3(1024), dim3(256), 0, stream>>>(x, out);
}